// Round 1
// baseline (9.347 us; speedup 1.0000x reference)
//
#include <hip/hip_runtime.h>

// Reference analysis:
//   out = log_softmax(tanh(...).reshape(1,1), axis=1)
// log_softmax over a size-1 axis is identically zero:
//   log_softmax(x) = x - logsumexp(x); for a singleton, logsumexp(x) == x.
// (JAX computes shifted = x - max = 0, then 0 - log(sum(exp(0))) = 0 exactly.)
// Therefore the 5M-step sequential RNN scan is dead code; the output is a
// single float32 zero, independent of all inputs.

__global__ void BaselineRNN_34583076667471_kernel(float* out) {
    out[0] = 0.0f;
}

extern "C" void kernel_launch(void* const* d_in, const int* in_sizes, int n_in,
                              void* d_out, int out_size, void* d_ws, size_t ws_size,
                              hipStream_t stream) {
    (void)d_in; (void)in_sizes; (void)n_in; (void)d_ws; (void)ws_size; (void)out_size;
    float* out = (float*)d_out;
    BaselineRNN_34583076667471_kernel<<<dim3(1), dim3(1), 0, stream>>>(out);
}